// Round 15
// baseline (93.750 us; speedup 1.0000x reference)
//
#include <hip/hip_runtime.h>
#include <math.h>

#define N_NODES 50000
#define N_EDGES 1200000
#define IN_DIM  256
#define OUT_DIM 64
#define SLOPE   0.2f
#define BNODES  64           // nodes per bucket: b = dst>>6, dl = dst&63
#define NBKT    782          // ceil(50000/64)
#define NBKT_PAD 1024
#define EPB     1024         // edges per k_bin chunk
#define NCHUNK  1172         // ceil(1200000/1024)
#define BCAP    2048         // max raw edges per bucket (mean 1536, +13 sigma)
#define SSTRIDE 2240         // padded lEdge capacity (BCAP + 64*3, x4)

typedef unsigned int   uint;
typedef unsigned short ushort;
typedef float  f32x4  __attribute__((ext_vector_type(4)));
typedef short  short8 __attribute__((ext_vector_type(8)));

__device__ inline ushort bf16_rne(float f) {
    uint u = __float_as_uint(f);
    u += 0x7FFF + ((u >> 16) & 1);
    return (ushort)(u >> 16);
}
__device__ inline float bf16_f32(ushort s) {
    return __uint_as_float(((uint)s) << 16);
}
__device__ inline ushort f32_f16(float f) {
    _Float16 h = (_Float16)f;
    return __builtin_bit_cast(ushort, h);
}
__device__ inline float f16_f32(ushort u) {
    return (float)__builtin_bit_cast(_Float16, u);
}
__device__ inline int waveInclScan(int v, int lane) {
    #pragma unroll
    for (int off = 1; off < 64; off <<= 1) {
        int x = __shfl_up(v, off);
        if (lane >= off) v += x;
    }
    return v;
}

// ---------------------------------------------------------------------------
// K0: blocks 0..NCHUNK-1: per-chunk bucket-grouping of 1024 edges (block-major
// output, no global placement/atomics). binned[c*EPB+i] = (dl<<16)|src grouped
// by bucket; tab[c*1024+b] = (localOffset<<11)|count. Wave-shfl scan (1
// barrier instead of 16). Blocks NCHUNK..: W -> bf16 hi/lo prep.
// ---------------------------------------------------------------------------
__global__ __launch_bounds__(256) void k_binprep(const int* __restrict__ src,
                                                 const int* __restrict__ dst,
                                                 const float* __restrict__ Wfc,
                                                 ushort* __restrict__ Whi,
                                                 ushort* __restrict__ Wlo,
                                                 uint* __restrict__ binned,
                                                 uint* __restrict__ tab) {
    if (blockIdx.x >= NCHUNK) {
        int i = (blockIdx.x - NCHUNK) * 256 + threadIdx.x;
        float f = Wfc[i];
        ushort hi = bf16_rne(f);
        Whi[i] = hi;
        Wlo[i] = bf16_rne(f - bf16_f32(hi));
        return;
    }
    __shared__ uint staged[EPB];           // 4 KB
    __shared__ int lhist[NBKT_PAD];        // 4 KB
    __shared__ int lcur[NBKT_PAD];         // 4 KB
    __shared__ int wsums[4];
    const int t = threadIdx.x;
    const int lane = t & 63, wid = t >> 6;
    const int c = blockIdx.x;
    const int base = c * EPB;
    const int n = min(EPB, N_EDGES - base);   // multiple of 4

    ((int4*)lhist)[t] = int4{0, 0, 0, 0};
    __syncthreads();

    int4 d4, s4;
    bool act = (4 * t < n);
    if (act) {
        d4 = ((const int4*)(dst + base))[t];
        s4 = ((const int4*)(src + base))[t];
        atomicAdd(&lhist[d4.x >> 6], 1);
        atomicAdd(&lhist[d4.y >> 6], 1);
        atomicAdd(&lhist[d4.z >> 6], 1);
        atomicAdd(&lhist[d4.w >> 6], 1);
    }
    __syncthreads();

    int4 hv = ((const int4*)lhist)[t];
    int lsum = hv.x + hv.y + hv.z + hv.w;
    int incl = waveInclScan(lsum, lane);
    if (lane == 63) wsums[wid] = incl;
    __syncthreads();
    int wbase = 0;
    #pragma unroll
    for (int w = 0; w < 4; ++w) if (w < wid) wbase += wsums[w];
    int excl = wbase + incl - lsum;

    int p0 = excl, p1 = p0 + hv.x, p2 = p1 + hv.y, p3 = p2 + hv.z;
    lcur[4 * t]     = p0;
    lcur[4 * t + 1] = p1;
    lcur[4 * t + 2] = p2;
    lcur[4 * t + 3] = p3;
    uint4 te;
    te.x = ((uint)p0 << 11) | (uint)hv.x;
    te.y = ((uint)p1 << 11) | (uint)hv.y;
    te.z = ((uint)p2 << 11) | (uint)hv.z;
    te.w = ((uint)p3 << 11) | (uint)hv.w;
    ((uint4*)(tab + (size_t)c * NBKT_PAD))[t] = te;
    __syncthreads();

    if (act) {
        int dd[4] = {d4.x, d4.y, d4.z, d4.w};
        int ss[4] = {s4.x, s4.y, s4.z, s4.w};
        #pragma unroll
        for (int u = 0; u < 4; ++u) {
            int b = dd[u] >> 6, dl = dd[u] & 63;
            int slot = atomicAdd(&lcur[b], 1);
            staged[slot] = ((uint)dl << 16) | (uint)ss[u];
        }
    }
    __syncthreads();
    #pragma unroll
    for (int k = 0; k < EPB / 256; ++k) {
        int i = k * 256 + t;
        if (i < n) binned[base + i] = staged[i];
    }
}

// ---------------------------------------------------------------------------
// K1: z = h @ W^T via mfma_f32_16x16x32_bf16. A = bf16(h) hi only; W is
// precomputed hi+lo => 2 MFMAs per (ks,n). One wave / 16 nodes, no LDS.
// Fused sS/sD. z stored f16.
// ---------------------------------------------------------------------------
__global__ __launch_bounds__(64) void k_gemm(const float* __restrict__ h,
                                             const ushort* __restrict__ Whi,
                                             const ushort* __restrict__ Wlo,
                                             const float* __restrict__ Wattn,
                                             ushort* __restrict__ zh,
                                             float* __restrict__ sS,
                                             float* __restrict__ sD) {
    const int l   = threadIdx.x;
    const int r16 = l & 15;
    const int g   = l >> 4;
    const int base = blockIdx.x * 16;

    const float*  ha = h   + (size_t)(base + r16) * IN_DIM + g * 8;
    const ushort* wh = Whi + (size_t)r16 * IN_DIM + g * 8;
    const ushort* wl = Wlo + (size_t)r16 * IN_DIM + g * 8;

    f32x4 c[4] = {{0,0,0,0},{0,0,0,0},{0,0,0,0},{0,0,0,0}};

    #pragma unroll
    for (int ks = 0; ks < 8; ++ks) {
        float4 a0 = *(const float4*)(ha + ks * 32);
        float4 a1 = *(const float4*)(ha + ks * 32 + 4);
        float af[8] = {a0.x, a0.y, a0.z, a0.w, a1.x, a1.y, a1.z, a1.w};
        short8 ahi;
        #pragma unroll
        for (int i = 0; i < 8; ++i) ahi[i] = (short)bf16_rne(af[i]);
        #pragma unroll
        for (int n = 0; n < 4; ++n) {
            short8 bh = *(const short8*)(wh + n * 16 * IN_DIM + ks * 32);
            short8 bl = *(const short8*)(wl + n * 16 * IN_DIM + ks * 32);
            c[n] = __builtin_amdgcn_mfma_f32_16x16x32_bf16(ahi, bh, c[n], 0, 0, 0);
            c[n] = __builtin_amdgcn_mfma_f32_16x16x32_bf16(ahi, bl, c[n], 0, 0, 0);
        }
    }

    float aSv[4], aDv[4];
    #pragma unroll
    for (int n = 0; n < 4; ++n) {
        aSv[n] = Wattn[n * 16 + r16];
        aDv[n] = Wattn[OUT_DIM + n * 16 + r16];
    }
    #pragma unroll
    for (int r = 0; r < 4; ++r) {
        int node = base + g * 4 + r;
        float ss = 0.f, sd = 0.f;
        #pragma unroll
        for (int n = 0; n < 4; ++n) {
            float v = c[n][r];
            zh[(size_t)node * OUT_DIM + n * 16 + r16] = f32_f16(v);
            ss += v * aSv[n];
            sd += v * aDv[n];
        }
        ss += __shfl_xor(ss, 1); ss += __shfl_xor(ss, 2);
        ss += __shfl_xor(ss, 4); ss += __shfl_xor(ss, 8);
        sd += __shfl_xor(sd, 1); sd += __shfl_xor(sd, 2);
        sd += __shfl_xor(sd, 4); sd += __shfl_xor(sd, 8);
        if (r16 == 0) { sS[node] = ss; sD[node] = sd; }
    }
}

// ---------------------------------------------------------------------------
// K2: FUSED sort + aggregation per 64-node bucket.
//  phase 1: gather bucket edges from block-major runs via tab -> lstage + hist
//  phase 2: pad-to-x4 wave-scan; dummy (ex=0) fill
//  phase 3: counting-sort permute with fused exp -> lEdge in LDS
//  phase 4: quarter-wave register aggregation (16 lanes/edge, lane = 4 dims
//           via uint2 gather, unroll-4 MLP), per-wave 16 nodes; ELU + float4.
// No srcEx/rowptr/cnt globals, no extra launch.
// ---------------------------------------------------------------------------
__global__ __launch_bounds__(256) void k_sortagg(const uint* __restrict__ binned,
                                                 const uint* __restrict__ tab,
                                                 const float* __restrict__ sS,
                                                 const float* __restrict__ sD,
                                                 const uint2* __restrict__ zrow,
                                                 float* __restrict__ out) {
    __shared__ uint lstage[BCAP];          // 8 KB
    __shared__ uint lEdge[SSTRIDE];        // 8.75 KB
    __shared__ int lhist[64], lcur[64], lpbeg[64], lpc[64];
    __shared__ float ldsD[64];
    __shared__ int wsums[4];
    const int b = blockIdx.x, t = threadIdx.x;
    const int lane = t & 63, wid = t >> 6;
    const int node0 = b << 6;
    if (t < 64) {
        lhist[t] = 0;
        int nd = node0 + t;
        ldsD[t] = (nd < N_NODES) ? sD[nd] : 0.f;
    }
    __syncthreads();

    // phase 1a: walk my chunks' tab entries, count my edges
    uint runs[5];
    int nck = 0, myCnt = 0;
    for (int c = t; c < NCHUNK; c += 256) {
        uint e = tab[(size_t)c * NBKT_PAD + b];
        runs[nck++] = e;
        myCnt += (int)(e & 0x7FF);
    }
    int incl = waveInclScan(myCnt, lane);
    if (lane == 63) wsums[wid] = incl;
    __syncthreads();
    int wbase = 0;
    #pragma unroll
    for (int w = 0; w < 4; ++w) if (w < wid) wbase += wsums[w];
    int pos = wbase + incl - myCnt;
    int n = 0;
    #pragma unroll
    for (int w = 0; w < 4; ++w) n += wsums[w];

    // phase 1b: gather my runs into lstage + dl histogram
    {
        int k = 0;
        for (int c = t; c < NCHUNK; c += 256, ++k) {
            uint e = runs[k];
            int cnt = (int)(e & 0x7FF);
            const uint* pB = binned + (size_t)c * EPB + (e >> 11);
            for (int i = 0; i < cnt; ++i) {
                uint w = pB[i];
                lstage[pos++] = w;
                atomicAdd(&lhist[w >> 16], 1);
            }
        }
    }
    __syncthreads();

    // phase 2: pad-to-x4 wave-scan over 64 nodes (wave 0 only); dummy fill
    if (t < 64) {
        int hc = lhist[t];
        int pc = (hc + 3) & ~3;
        int pincl = waveInclScan(pc, t);
        int pexcl = pincl - pc;
        lpbeg[t] = pexcl;
        lcur[t] = pexcl;
        lpc[t] = pc;
        for (int j = hc; j < pc; ++j) lEdge[pexcl + j] = 0;   // dummy: src=0, ex=0
    }
    __syncthreads();

    // phase 3: permute + fused exp into lEdge
    for (int i = t; i < n; i += 256) {
        uint w = lstage[i];
        int dl = (int)(w >> 16);
        int s  = (int)(w & 0xFFFF);
        float e = sS[s] + ldsD[dl];
        e = e > 0.f ? e : SLOPE * e;
        ushort exb = f32_f16(__expf(e));
        int slot = atomicAdd(&lcur[dl], 1);
        lEdge[slot] = ((w & 0xFFFFu) << 16) | (uint)exb;
    }
    __syncthreads();

    // phase 4: quarter-wave register aggregation; wave wid -> 16 nodes
    const int q = lane >> 4, ql = lane & 15;
    #pragma unroll 1
    for (int nl0 = 0; nl0 < 16; ++nl0) {
        int nl = wid * 16 + nl0;
        int beg = lpbeg[nl];
        int cnt4 = lpc[nl];
        float a0 = 0.f, a1 = 0.f, a2 = 0.f, a3 = 0.f, den = 0.f;
        #pragma unroll 4
        for (int i = 0; i < cnt4; i += 4) {
            uint w = lEdge[beg + i + q];
            uint2 zp = zrow[((w >> 16) << 4) + ql];
            float ex = f16_f32((ushort)(w & 0xFFFF));
            a0 += ex * f16_f32((ushort)(zp.x & 0xFFFF));
            a1 += ex * f16_f32((ushort)(zp.x >> 16));
            a2 += ex * f16_f32((ushort)(zp.y & 0xFFFF));
            a3 += ex * f16_f32((ushort)(zp.y >> 16));
            den += ex;
        }
        a0 += __shfl_xor(a0, 16); a0 += __shfl_xor(a0, 32);
        a1 += __shfl_xor(a1, 16); a1 += __shfl_xor(a1, 32);
        a2 += __shfl_xor(a2, 16); a2 += __shfl_xor(a2, 32);
        a3 += __shfl_xor(a3, 16); a3 += __shfl_xor(a3, 32);
        den += __shfl_xor(den, 16); den += __shfl_xor(den, 32);
        int node = node0 + nl;
        if (q == 0 && node < N_NODES) {
            float inv = den > 0.f ? 1.f / den : 0.f;
            float r0 = a0 * inv, r1 = a1 * inv, r2 = a2 * inv, r3 = a3 * inv;
            r0 = r0 > 0.f ? r0 : expm1f(r0);
            r1 = r1 > 0.f ? r1 : expm1f(r1);
            r2 = r2 > 0.f ? r2 : expm1f(r2);
            r3 = r3 > 0.f ? r3 : expm1f(r3);
            float4 r = make_float4(r0, r1, r2, r3);
            ((float4*)out)[(size_t)node * 16 + ql] = r;
        }
    }
}

static inline char* alignup(char* p) {
    return (char*)(((uintptr_t)p + 63) & ~(uintptr_t)63);
}

extern "C" void kernel_launch(void* const* d_in, const int* in_sizes, int n_in,
                              void* d_out, int out_size, void* d_ws, size_t ws_size,
                              hipStream_t stream) {
    const float* h     = (const float*)d_in[0];
    const float* Wfc   = (const float*)d_in[1];
    const float* Wattn = (const float*)d_in[2];
    const int*   src   = (const int*)d_in[3];
    const int*   dst   = (const int*)d_in[4];
    float* out = (float*)d_out;

    // workspace layout (64B-aligned regions)
    char* p = (char*)d_ws;
    uint*   binned  = (uint*)p;   p = alignup(p + (size_t)N_EDGES * 4);
    uint*   tab     = (uint*)p;   p = alignup(p + (size_t)NCHUNK * NBKT_PAD * 4);
    float*  sS      = (float*)p;  p = alignup(p + (size_t)N_NODES * 4);
    float*  sD      = (float*)p;  p = alignup(p + (size_t)N_NODES * 4);
    ushort* Whi     = (ushort*)p; p = alignup(p + OUT_DIM * IN_DIM * 2);
    ushort* Wlo     = (ushort*)p; p = alignup(p + OUT_DIM * IN_DIM * 2);
    ushort* zh      = (ushort*)p;

    k_binprep<<<NCHUNK + 64, 256, 0, stream>>>(src, dst, Wfc, Whi, Wlo, binned, tab);
    k_gemm<<<N_NODES / 16, 64, 0, stream>>>(h, Whi, Wlo, Wattn, zh, sS, sD);
    k_sortagg<<<NBKT, 256, 0, stream>>>(binned, tab, sS, sD, (const uint2*)zh, out);
}

// Round 16
// 92.109 us; speedup vs baseline: 1.0178x; 1.0178x over previous
//
#include <hip/hip_runtime.h>
#include <math.h>

#define N_NODES 50000
#define N_EDGES 1200000
#define IN_DIM  256
#define OUT_DIM 64
#define SLOPE   0.2f
#define BNODES  64           // nodes per bucket: b = dst>>6, dl = dst&63
#define NBKT    782          // ceil(50000/64)
#define NBKT_PAD 1024
#define EPB     1024         // edges per k_bin chunk
#define NCHUNK  1172         // ceil(1200000/1024)
#define BCAP    2048         // max raw edges per bucket (mean 1536, +13 sigma)
#define SSTRIDE 2304         // padded srcEx stride per bucket (x4 node segments)

typedef unsigned int   uint;
typedef unsigned short ushort;
typedef float  f32x4  __attribute__((ext_vector_type(4)));
typedef short  short8 __attribute__((ext_vector_type(8)));

__device__ inline ushort bf16_rne(float f) {
    uint u = __float_as_uint(f);
    u += 0x7FFF + ((u >> 16) & 1);
    return (ushort)(u >> 16);
}
__device__ inline float bf16_f32(ushort s) {
    return __uint_as_float(((uint)s) << 16);
}
__device__ inline ushort f32_f16(float f) {
    _Float16 h = (_Float16)f;
    return __builtin_bit_cast(ushort, h);
}
__device__ inline float f16_f32(ushort u) {
    return (float)__builtin_bit_cast(_Float16, u);
}
__device__ inline int waveInclScan(int v, int lane) {
    #pragma unroll
    for (int off = 1; off < 64; off <<= 1) {
        int x = __shfl_up(v, off);
        if (lane >= off) v += x;
    }
    return v;
}

// ---------------------------------------------------------------------------
// K0: blocks 0..NCHUNK-1: per-chunk bucket-grouping of 1024 edges (block-major
// output, no global placement/atomics). binned[c*EPB+i] = (dl<<16)|src grouped
// by bucket; tab[c*1024+b] = (localOffset<<11)|count. Wave-shfl scan.
// Blocks NCHUNK..: W -> bf16 hi/lo prep.
// ---------------------------------------------------------------------------
__global__ __launch_bounds__(256) void k_binprep(const int* __restrict__ src,
                                                 const int* __restrict__ dst,
                                                 const float* __restrict__ Wfc,
                                                 ushort* __restrict__ Whi,
                                                 ushort* __restrict__ Wlo,
                                                 uint* __restrict__ binned,
                                                 uint* __restrict__ tab) {
    if (blockIdx.x >= NCHUNK) {
        int i = (blockIdx.x - NCHUNK) * 256 + threadIdx.x;
        float f = Wfc[i];
        ushort hi = bf16_rne(f);
        Whi[i] = hi;
        Wlo[i] = bf16_rne(f - bf16_f32(hi));
        return;
    }
    __shared__ uint staged[EPB];           // 4 KB
    __shared__ int lhist[NBKT_PAD];        // 4 KB
    __shared__ int lcur[NBKT_PAD];         // 4 KB
    __shared__ int wsums[4];
    const int t = threadIdx.x;
    const int lane = t & 63, wid = t >> 6;
    const int c = blockIdx.x;
    const int base = c * EPB;
    const int n = min(EPB, N_EDGES - base);   // multiple of 4

    ((int4*)lhist)[t] = int4{0, 0, 0, 0};
    __syncthreads();

    int4 d4, s4;
    bool act = (4 * t < n);
    if (act) {
        d4 = ((const int4*)(dst + base))[t];
        s4 = ((const int4*)(src + base))[t];
        atomicAdd(&lhist[d4.x >> 6], 1);
        atomicAdd(&lhist[d4.y >> 6], 1);
        atomicAdd(&lhist[d4.z >> 6], 1);
        atomicAdd(&lhist[d4.w >> 6], 1);
    }
    __syncthreads();

    int4 hv = ((const int4*)lhist)[t];
    int lsum = hv.x + hv.y + hv.z + hv.w;
    int incl = waveInclScan(lsum, lane);
    if (lane == 63) wsums[wid] = incl;
    __syncthreads();
    int wbase = 0;
    #pragma unroll
    for (int w = 0; w < 4; ++w) if (w < wid) wbase += wsums[w];
    int excl = wbase + incl - lsum;

    int p0 = excl, p1 = p0 + hv.x, p2 = p1 + hv.y, p3 = p2 + hv.z;
    lcur[4 * t]     = p0;
    lcur[4 * t + 1] = p1;
    lcur[4 * t + 2] = p2;
    lcur[4 * t + 3] = p3;
    uint4 te;
    te.x = ((uint)p0 << 11) | (uint)hv.x;
    te.y = ((uint)p1 << 11) | (uint)hv.y;
    te.z = ((uint)p2 << 11) | (uint)hv.z;
    te.w = ((uint)p3 << 11) | (uint)hv.w;
    ((uint4*)(tab + (size_t)c * NBKT_PAD))[t] = te;
    __syncthreads();

    if (act) {
        int dd[4] = {d4.x, d4.y, d4.z, d4.w};
        int ss[4] = {s4.x, s4.y, s4.z, s4.w};
        #pragma unroll
        for (int u = 0; u < 4; ++u) {
            int b = dd[u] >> 6, dl = dd[u] & 63;
            int slot = atomicAdd(&lcur[b], 1);
            staged[slot] = ((uint)dl << 16) | (uint)ss[u];
        }
    }
    __syncthreads();
    #pragma unroll
    for (int k = 0; k < EPB / 256; ++k) {
        int i = k * 256 + t;
        if (i < n) binned[base + i] = staged[i];
    }
}

// ---------------------------------------------------------------------------
// K1: z = h @ W^T via mfma_f32_16x16x32_bf16. A = bf16(h) hi only; W is
// precomputed hi+lo => 2 MFMAs per (ks,n). One wave / 16 nodes, no LDS.
// Fused sS/sD. z stored f16.
// ---------------------------------------------------------------------------
__global__ __launch_bounds__(64) void k_gemm(const float* __restrict__ h,
                                             const ushort* __restrict__ Whi,
                                             const ushort* __restrict__ Wlo,
                                             const float* __restrict__ Wattn,
                                             ushort* __restrict__ zh,
                                             float* __restrict__ sS,
                                             float* __restrict__ sD) {
    const int l   = threadIdx.x;
    const int r16 = l & 15;
    const int g   = l >> 4;
    const int base = blockIdx.x * 16;

    const float*  ha = h   + (size_t)(base + r16) * IN_DIM + g * 8;
    const ushort* wh = Whi + (size_t)r16 * IN_DIM + g * 8;
    const ushort* wl = Wlo + (size_t)r16 * IN_DIM + g * 8;

    f32x4 c[4] = {{0,0,0,0},{0,0,0,0},{0,0,0,0},{0,0,0,0}};

    #pragma unroll
    for (int ks = 0; ks < 8; ++ks) {
        float4 a0 = *(const float4*)(ha + ks * 32);
        float4 a1 = *(const float4*)(ha + ks * 32 + 4);
        float af[8] = {a0.x, a0.y, a0.z, a0.w, a1.x, a1.y, a1.z, a1.w};
        short8 ahi;
        #pragma unroll
        for (int i = 0; i < 8; ++i) ahi[i] = (short)bf16_rne(af[i]);
        #pragma unroll
        for (int n = 0; n < 4; ++n) {
            short8 bh = *(const short8*)(wh + n * 16 * IN_DIM + ks * 32);
            short8 bl = *(const short8*)(wl + n * 16 * IN_DIM + ks * 32);
            c[n] = __builtin_amdgcn_mfma_f32_16x16x32_bf16(ahi, bh, c[n], 0, 0, 0);
            c[n] = __builtin_amdgcn_mfma_f32_16x16x32_bf16(ahi, bl, c[n], 0, 0, 0);
        }
    }

    float aSv[4], aDv[4];
    #pragma unroll
    for (int n = 0; n < 4; ++n) {
        aSv[n] = Wattn[n * 16 + r16];
        aDv[n] = Wattn[OUT_DIM + n * 16 + r16];
    }
    #pragma unroll
    for (int r = 0; r < 4; ++r) {
        int node = base + g * 4 + r;
        float ss = 0.f, sd = 0.f;
        #pragma unroll
        for (int n = 0; n < 4; ++n) {
            float v = c[n][r];
            zh[(size_t)node * OUT_DIM + n * 16 + r16] = f32_f16(v);
            ss += v * aSv[n];
            sd += v * aDv[n];
        }
        ss += __shfl_xor(ss, 1); ss += __shfl_xor(ss, 2);
        ss += __shfl_xor(ss, 4); ss += __shfl_xor(ss, 8);
        sd += __shfl_xor(sd, 1); sd += __shfl_xor(sd, 2);
        sd += __shfl_xor(sd, 4); sd += __shfl_xor(sd, 8);
        if (r16 == 0) { sS[node] = ss; sD[node] = sd; }
    }
}

// ---------------------------------------------------------------------------
// K2: per-64-node-bucket counting sort with fused exp (R10-verified). Gathers
// bucket edges from block-major runs via tab, stages in LDS, sorts by dl,
// writes srcEx with x4-ALIGNED node segments (pad slots never read; cntArr
// stores RAW count) + rowptrFine.
// ---------------------------------------------------------------------------
__global__ __launch_bounds__(256) void k_sort(const uint* __restrict__ binned,
                                              const uint* __restrict__ tab,
                                              const float* __restrict__ sS,
                                              const float* __restrict__ sD,
                                              uint* __restrict__ srcEx,
                                              int* __restrict__ rowptrFine,
                                              int* __restrict__ cntArr) {
    __shared__ uint lstage[BCAP];          // 8 KB
    __shared__ uint lEdge[SSTRIDE];        // 9 KB
    __shared__ int lhist[64], lcur[64], ws[256];
    __shared__ float ldsD[64];
    __shared__ int sPtot;
    const int b = blockIdx.x, t = threadIdx.x;
    const int node = (b << 6) + t;
    if (t < 64) {
        lhist[t] = 0;
        ldsD[t] = (node < N_NODES) ? sD[node] : 0.f;
    }
    __syncthreads();

    // pass 1: walk my chunks' tab entries, count my edges
    uint runs[5];
    int nck = 0, myCnt = 0;
    for (int c = t; c < NCHUNK; c += 256) {
        uint e = tab[(size_t)c * NBKT_PAD + b];
        runs[nck++] = e;
        myCnt += (int)(e & 0x7FF);
    }
    ws[t] = myCnt; __syncthreads();
    #pragma unroll
    for (int off = 1; off < 256; off <<= 1) {
        int x = (t >= off) ? ws[t - off] : 0;
        __syncthreads(); ws[t] += x; __syncthreads();
    }
    int pos = ws[t] - myCnt;
    int n = ws[255];
    __syncthreads();

    // pass 2: gather my runs into lstage + dl histogram
    {
        int k = 0;
        for (int c = t; c < NCHUNK; c += 256, ++k) {
            uint e = runs[k];
            int cnt = (int)(e & 0x7FF);
            const uint* pB = binned + (size_t)c * EPB + (e >> 11);
            for (int i = 0; i < cnt; ++i) {
                uint w = pB[i];
                lstage[pos++] = w;
                atomicAdd(&lhist[w >> 16], 1);
            }
        }
    }
    __syncthreads();

    // pad-to-x4 scan over 64 nodes
    int pc = 0;
    if (t < 64) { pc = (lhist[t] + 3) & ~3; ws[t] = pc; }
    __syncthreads();
    #pragma unroll
    for (int off = 1; off < 64; off <<= 1) {
        int x = 0;
        if (t < 64 && t >= off) x = ws[t - off];
        __syncthreads();
        if (t < 64) ws[t] += x;
        __syncthreads();
    }
    if (t < 64) {
        int pexcl = ws[t] - pc;
        lcur[t] = pexcl;
        if (node < N_NODES) {
            rowptrFine[node] = b * SSTRIDE + pexcl;
            cntArr[node] = lhist[t];      // RAW count
        }
        if (t == 63) sPtot = ws[63];
    }
    __syncthreads();

    // permute + fused exp
    for (int i = t; i < n; i += 256) {
        uint w = lstage[i];
        int dl = (int)(w >> 16);
        int s  = (int)(w & 0xFFFF);
        float e = sS[s] + ldsD[dl];
        e = e > 0.f ? e : SLOPE * e;
        ushort exb = f32_f16(__expf(e));
        int slot = atomicAdd(&lcur[dl], 1);
        lEdge[slot] = ((w & 0xFFFFu) << 16) | (uint)exb;
    }
    __syncthreads();

    int ptot = sPtot;
    uint* dstp = srcEx + (size_t)b * SSTRIDE;
    for (int i = t; i < ptot; i += 256) dstp[i] = lEdge[i];
}

// ---------------------------------------------------------------------------
// K3: one wave per dst node, paired halves, MLP-8 (R10-verified best): each
// half-wave keeps 8 gathers in flight (16 edges/wave-iter); uint4 srcEx loads
// (16B-aligned by the padded layout); lane covers 2 output dims via packed-f16
// dword; den in-register; cross-half shfl combine; ELU + float2 store.
// ---------------------------------------------------------------------------
__global__ __launch_bounds__(256) void k_aggc(const uint* __restrict__ zh32,
                                              const uint* __restrict__ srcEx,
                                              const int* __restrict__ rowptr,
                                              const int* __restrict__ cntArr,
                                              float* __restrict__ out) {
    int node = blockIdx.x * 4 + (threadIdx.x >> 6);
    int lane = threadIdx.x & 63;
    int half = lane >> 5, pl = lane & 31;
    int beg = rowptr[node];
    int cnt = cntArr[node];
    float acc0 = 0.f, acc1 = 0.f, den = 0.f;
    int i = 0;
    for (; i + 16 <= cnt; i += 16) {
        const uint4* p4 = (const uint4*)(srcEx + beg + i + half * 8);
        uint4 wa = p4[0], wb = p4[1];
        uint w[8] = {wa.x, wa.y, wa.z, wa.w, wb.x, wb.y, wb.z, wb.w};
        uint zp[8];
        #pragma unroll
        for (int u = 0; u < 8; ++u) zp[u] = zh32[((w[u] >> 16) << 5) + pl];
        #pragma unroll
        for (int u = 0; u < 8; ++u) {
            float ex = f16_f32((ushort)(w[u] & 0xFFFF));
            acc0 += ex * f16_f32((ushort)(zp[u] & 0xFFFF));
            acc1 += ex * f16_f32((ushort)(zp[u] >> 16));
            den  += ex;
        }
    }
    if (i + 8 <= cnt) {
        uint4 wa = *(const uint4*)(srcEx + beg + i + half * 4);
        uint w[4] = {wa.x, wa.y, wa.z, wa.w};
        uint zp[4];
        #pragma unroll
        for (int u = 0; u < 4; ++u) zp[u] = zh32[((w[u] >> 16) << 5) + pl];
        #pragma unroll
        for (int u = 0; u < 4; ++u) {
            float ex = f16_f32((ushort)(w[u] & 0xFFFF));
            acc0 += ex * f16_f32((ushort)(zp[u] & 0xFFFF));
            acc1 += ex * f16_f32((ushort)(zp[u] >> 16));
            den  += ex;
        }
        i += 8;
    }
    for (; i + 2 <= cnt; i += 2) {
        uint w = srcEx[beg + i + half];
        uint zp = zh32[((w >> 16) << 5) + pl];
        float ex = f16_f32((ushort)(w & 0xFFFF));
        acc0 += ex * f16_f32((ushort)(zp & 0xFFFF));
        acc1 += ex * f16_f32((ushort)(zp >> 16));
        den  += ex;
    }
    if (i < cnt && half == 0) {
        uint w = srcEx[beg + i];
        uint zp = zh32[((w >> 16) << 5) + pl];
        float ex = f16_f32((ushort)(w & 0xFFFF));
        acc0 += ex * f16_f32((ushort)(zp & 0xFFFF));
        acc1 += ex * f16_f32((ushort)(zp >> 16));
        den  += ex;
    }
    acc0 += __shfl_xor(acc0, 32);
    acc1 += __shfl_xor(acc1, 32);
    den  += __shfl_xor(den, 32);
    if (half == 0) {
        float r0 = den > 0.f ? acc0 / den : 0.f;
        float r1 = den > 0.f ? acc1 / den : 0.f;
        r0 = r0 > 0.f ? r0 : expm1f(r0);
        r1 = r1 > 0.f ? r1 : expm1f(r1);
        ((float2*)out)[(((size_t)node) << 5) + pl] = make_float2(r0, r1);
    }
}

static inline char* alignup(char* p) {
    return (char*)(((uintptr_t)p + 63) & ~(uintptr_t)63);
}

extern "C" void kernel_launch(void* const* d_in, const int* in_sizes, int n_in,
                              void* d_out, int out_size, void* d_ws, size_t ws_size,
                              hipStream_t stream) {
    const float* h     = (const float*)d_in[0];
    const float* Wfc   = (const float*)d_in[1];
    const float* Wattn = (const float*)d_in[2];
    const int*   src   = (const int*)d_in[3];
    const int*   dst   = (const int*)d_in[4];
    float* out = (float*)d_out;

    // workspace layout (64B-aligned regions)
    char* p = (char*)d_ws;
    uint*   binned  = (uint*)p;   p = alignup(p + (size_t)N_EDGES * 4);
    uint*   tab     = (uint*)p;   p = alignup(p + (size_t)NCHUNK * NBKT_PAD * 4);
    uint*   srcEx   = (uint*)p;   p = alignup(p + (size_t)NBKT * SSTRIDE * 4);
    int*    rowptrF = (int*)p;    p = alignup(p + (size_t)N_NODES * 4);
    int*    cntArr  = (int*)p;    p = alignup(p + (size_t)N_NODES * 4);
    float*  sS      = (float*)p;  p = alignup(p + (size_t)N_NODES * 4);
    float*  sD      = (float*)p;  p = alignup(p + (size_t)N_NODES * 4);
    ushort* Whi     = (ushort*)p; p = alignup(p + OUT_DIM * IN_DIM * 2);
    ushort* Wlo     = (ushort*)p; p = alignup(p + OUT_DIM * IN_DIM * 2);
    ushort* zh      = (ushort*)p;

    k_binprep<<<NCHUNK + 64, 256, 0, stream>>>(src, dst, Wfc, Whi, Wlo, binned, tab);
    k_gemm<<<N_NODES / 16, 64, 0, stream>>>(h, Whi, Wlo, Wattn, zh, sS, sD);
    k_sort<<<NBKT, 256, 0, stream>>>(binned, tab, sS, sD, srcEx, rowptrF, cntArr);
    k_aggc<<<N_NODES / 4, 256, 0, stream>>>((const uint*)zh, srcEx, rowptrF, cntArr, out);
}